// Round 24
// baseline (114.017 us; speedup 1.0000x reference)
//
#include <hip/hip_runtime.h>
#include <hip/hip_bf16.h>

// Bloom MLP fused: h=X@W1^T+b1; g=gelu_tanh(h); out=g@W2^T+b2+residual
// X:[262144,64] f32, W1:[256,64], W2:[64,256], out:[262144,64] f32.
//
// Round 24 = r22 frame (best 63.3us; NT loads of r23 reverted) + 64 tokens
// per wave with tile-1 X loads in flight under tile-0 compute.
// r21 tried this and spilled (WRITE 66->206MB): fragment arrays passed via
// POINTER-typed lambda params forced stack allocation. Fix: macro-inlined
// tiles, all arrays named + constant-indexed (r2-r20 never spilled this way).
// Timeline per wave: ldX(tile0) -> stage W1/b1 -> cvt -> barrier ->
// ldX(tile1, stays outstanding) -> tile0 kb-loop+epilogue -> cvt(tile1) ->
// tile1 kb-loop+epilogue. Prologues halved (NBLK=1024).
//  - kappa-permuted W2 from global (32KB bf16 image, L1-hot), W1+b1 in LDS
//    (33KB -> 4 blocks/CU), fused kb-loop, ONE barrier, (256,4), nt stores.

typedef __attribute__((ext_vector_type(8))) short bf16x8;   // MFMA A/B frag
typedef __attribute__((ext_vector_type(4))) float f32x4;    // MFMA C/D frag
typedef __attribute__((ext_vector_type(4))) float f32x4v;   // nt-store vector
typedef __attribute__((ext_vector_type(4))) short short4v;  // packed 4x bf16

#define NBLK 1024    // 1024 blocks * 4 waves * 64 tokens = 262144

__device__ __forceinline__ short f2bf(float x) {
    union { __hip_bfloat16 h; short s; } u;
    u.h = __float2bfloat16(x);      // compiler pairs into v_cvt_pk_bf16_f32
    return u.s;
}

__device__ __forceinline__ float bloom_gelu(float x) {
    // 0.5*x*(1+tanh(0.79788456*(x+0.044715*x^3))) = x*(1 - 1/(e^{2u}+1))
    // 2u*log2(e) = 2.30220842*x + 0.10294325*x^3 -> v_exp_f32 (2^x) direct
    float x2 = x * x;
    float t1 = __builtin_fmaf(0.10294325f, x2, 2.30220842f);
    float e  = __builtin_exp2f(x * t1);
    float r  = __builtin_amdgcn_rcpf(e + 1.0f);
    return x - x * r;
}

// W1 LDS image: [256 rows][64 shorts], 8 slots of 8 shorts per row,
// slot XOR-swizzled by row&7.
__device__ __forceinline__ int w1_off(int row, int slot) {
    return row * 64 + ((slot ^ (row & 7)) << 3);
}

// async global->LDS, 16B per lane; dest lane-linear (base+lane*16)
__device__ __forceinline__ void gload_lds16(const void* src, void* dst) {
    __builtin_amdgcn_global_load_lds(
        (const __attribute__((address_space(1))) void*)src,
        (__attribute__((address_space(3))) void*)dst, 16, 0, 0);
}

// ---- pre-pass: ws image = [W1 swizzled bf16 32KB][W2 kappa-linear bf16 32KB]
// W2 col f bits: [7:4]=t [3:2]=q [1:0]=r -> kappa=[7:5]=t>>1 [4:3]=q [2]=t&1 [1:0]=r
__global__ __launch_bounds__(256) void cvt_weights(
    const float* __restrict__ W1, const float* __restrict__ W2,
    short* __restrict__ wsb)
{
    const int i4 = (blockIdx.x * 256 + threadIdx.x) * 4;   // 0..32764, step 4
    if (i4 < 16384) {
        const int row = i4 >> 6, col = i4 & 63;
        float4 v = *(const float4*)(W1 + i4);
        short4v o;
        o[0]=f2bf(v.x); o[1]=f2bf(v.y); o[2]=f2bf(v.z); o[3]=f2bf(v.w);
        *(short4v*)(wsb + w1_off(row, col >> 3) + (col & 7)) = o;
    } else {
        const int rel = i4 - 16384;
        const int d = rel >> 8, f = rel & 255;             // 4 f share t,q
        const int t = f >> 4, qq = (f >> 2) & 3;
        const int k4 = ((t >> 1) << 5) | (qq << 3) | ((t & 1) << 2);
        float4 v = *(const float4*)(W2 + rel);
        short4v o;
        o[0]=f2bf(v.x); o[1]=f2bf(v.y); o[2]=f2bf(v.z); o[3]=f2bf(v.w);
        *(short4v*)(wsb + 16384 + (d << 8) + k4) = o;      // linear kappa
    }
}

// load one 32-token tile's X into a named float4[2][4] (constant-indexed)
#define LDX(XD, TOKBASE)                                                     \
    _Pragma("unroll")                                                        \
    for (int m_ = 0; m_ < 2; ++m_) {                                         \
        const float* p_ = X + (size_t)((TOKBASE) + 16*m_ + c) * 64 + q*8;    \
        XD[m_][0] = *(const float4*)(p_);                                    \
        XD[m_][1] = *(const float4*)(p_ + 4);                                \
        XD[m_][2] = *(const float4*)(p_ + 32);                               \
        XD[m_][3] = *(const float4*)(p_ + 36);                               \
    }

// convert a named float4[2][4] to a1[2][2] bf16 fragments
#define CVT_A1(XD)                                                           \
    _Pragma("unroll")                                                        \
    for (int m_ = 0; m_ < 2; ++m_)                                           \
        _Pragma("unroll")                                                    \
        for (int kb_ = 0; kb_ < 2; ++kb_) {                                  \
            const float4 lo_ = XD[m_][2*kb_], hi_ = XD[m_][2*kb_ + 1];       \
            bf16x8 f_;                                                       \
            f_[0]=f2bf(lo_.x); f_[1]=f2bf(lo_.y); f_[2]=f2bf(lo_.z);         \
            f_[3]=f2bf(lo_.w); f_[4]=f2bf(hi_.x); f_[5]=f2bf(hi_.y);         \
            f_[6]=f2bf(hi_.z); f_[7]=f2bf(hi_.w);                            \
            a1[m_][kb_] = f_;                                                \
        }

// fused kb pipeline + epilogue for one 32-token tile (uses a1; inline)
#define RUN_TILE(TOK0)                                                       \
    {                                                                        \
        f32x4 acc2[2][4] = {{{0,0,0,0},{0,0,0,0},{0,0,0,0},{0,0,0,0}},       \
                            {{0,0,0,0},{0,0,0,0},{0,0,0,0},{0,0,0,0}}};      \
        _Pragma("unroll")                                                    \
        for (int kb = 0; kb < 8; ++kb) {                                     \
            bf16x8 w2f[4];                                                   \
            _Pragma("unroll")                                                \
            for (int dt = 0; dt < 4; ++dt)                                   \
                w2f[dt] = *(const bf16x8*)&Wb[16384 + (16*dt + c) * 256 +    \
                                              kb*32 + q*8];                  \
            bf16x8 pm[2];                                                    \
            _Pragma("unroll")                                                \
            for (int tt = 0; tt < 2; ++tt) {                                 \
                const int t_  = 2*kb + tt;                                   \
                const int row = 16*t_ + c;                                   \
                const bf16x8 w1a = *(const bf16x8*)&W1lds[w1_off(row, q)];   \
                const bf16x8 w1b = *(const bf16x8*)&W1lds[w1_off(row, 4+q)]; \
                const float4 b1v = *(const float4*)&Bl1[16*t_ + 4*q];        \
                _Pragma("unroll")                                            \
                for (int m = 0; m < 2; ++m) {                                \
                    f32x4 acc = {0.f, 0.f, 0.f, 0.f};                        \
                    acc = __builtin_amdgcn_mfma_f32_16x16x32_bf16(           \
                        w1a, a1[m][0], acc, 0, 0, 0);                        \
                    acc = __builtin_amdgcn_mfma_f32_16x16x32_bf16(           \
                        w1b, a1[m][1], acc, 0, 0, 0);                        \
                    _Pragma("unroll")                                        \
                    for (int r = 0; r < 4; ++r)                              \
                        pm[m][(tt << 2) + r] =                               \
                            f2bf(bloom_gelu(acc[r] + b1v[r]));               \
                }                                                            \
            }                                                                \
            _Pragma("unroll")                                                \
            for (int dt = 0; dt < 4; ++dt)                                   \
                _Pragma("unroll")                                            \
                for (int m = 0; m < 2; ++m)                                  \
                    acc2[m][dt] = __builtin_amdgcn_mfma_f32_16x16x32_bf16(   \
                        w2f[dt], pm[m], acc2[m][dt], 0, 0, 0);               \
        }                                                                    \
        _Pragma("unroll")                                                    \
        for (int m = 0; m < 2; ++m)                                          \
            _Pragma("unroll")                                                \
            for (int dt = 0; dt < 4; ++dt) {                                 \
                const size_t off =                                           \
                    (size_t)((TOK0) + 16*m + c) * 64 + 16*dt + 4*q;          \
                const float4 r4  = *(const float4*)(R + off);                \
                const float4 b2v = *(const float4*)(b2 + 16*dt + 4*q);       \
                f32x4v o;                                                    \
                o[0] = acc2[m][dt][0] + b2v.x + r4.x;                        \
                o[1] = acc2[m][dt][1] + b2v.y + r4.y;                        \
                o[2] = acc2[m][dt][2] + b2v.z + r4.z;                        \
                o[3] = acc2[m][dt][3] + b2v.w + r4.w;                        \
                __builtin_nontemporal_store(o, (f32x4v*)(out + off));        \
            }                                                                \
    }

template<bool PRE>
__global__ __launch_bounds__(256, 4) void bloom_mlp(
    const float* __restrict__ X,  const float* __restrict__ R,
    const float* __restrict__ W1, const float* __restrict__ b1,
    const float* __restrict__ W2, const float* __restrict__ b2,
    const short* __restrict__ Wb, float* __restrict__ out)
{
    __shared__ __align__(16) short W1lds[16384];   // 32 KB swizzled W1
    __shared__ __align__(16) float Bl1[256];       //  1 KB b1

    const int tid  = threadIdx.x;
    const int wid  = tid >> 6;      // wave 0..3 (independent after the barrier)
    const int lane = tid & 63;
    const int q    = lane >> 4;     // 0..3
    const int c    = lane & 15;     // 0..15
    const int tokW = blockIdx.x * 256 + wid * 64;  // wave owns 64 tokens

    // ---- tile-0 X issued now: flies across weight staging ----
    float4 xA[2][4];
    LDX(xA, tokW)

    // ---- stage W1 (32KB) + b1 (1KB) into LDS ----
    if constexpr (PRE) {
#pragma unroll
        for (int k = 0; k < 8; ++k) {
            const int s8 = (k * 256 + tid) * 8;            // short index
            gload_lds16(Wb + s8, &W1lds[s8]);
        }
        if (tid < 64) gload_lds16(b1 + tid * 4, &Bl1[tid * 4]);
    } else {
#pragma unroll
        for (int k = 0; k < 16; ++k) {
            const int i4 = (k * 256 + tid) * 4;            // W1 floats
            const int row = i4 >> 6, col = i4 & 63;
            float4 v = *(const float4*)(W1 + i4);
            short4v o;
            o[0]=f2bf(v.x); o[1]=f2bf(v.y); o[2]=f2bf(v.z); o[3]=f2bf(v.w);
            *(short4v*)&W1lds[w1_off(row, col >> 3) + (col & 7)] = o;
        }
        if (tid < 64) *(float4*)&Bl1[tid * 4] = *(const float4*)(b1 + tid * 4);
        // note: the PRE=false path keeps W2 reads via Wb unavailable; the
        // harness always provides ws >= 64KB, so PRE=true is the real path.
    }

    bf16x8 a1[2][2];
    CVT_A1(xA)            // waits only on this wave's tile-0 X

    __syncthreads();   // THE one barrier: W1/b1 staged (drains vm+lgkm)

    // ---- tile-1 X issued NOW: outstanding under all of tile-0 compute ----
    float4 xB[2][4];
    LDX(xB, tokW + 32)

    RUN_TILE(tokW)        // tile 0 (xB loads in flight underneath)

    CVT_A1(xB)            // xB landed long ago
    RUN_TILE(tokW + 32)   // tile 1
}

extern "C" void kernel_launch(void* const* d_in, const int* in_sizes, int n_in,
                              void* d_out, int out_size, void* d_ws, size_t ws_size,
                              hipStream_t stream) {
    const float* X  = (const float*)d_in[0];
    const float* R  = (const float*)d_in[1];
    const float* W1 = (const float*)d_in[2];
    const float* b1 = (const float*)d_in[3];
    const float* W2 = (const float*)d_in[4];
    const float* b2 = (const float*)d_in[5];
    float* out = (float*)d_out;
    (void)in_sizes; (void)n_in; (void)out_size;

    // PRE path requires ws for the bf16 weight image (W1 swz + W2 kappa).
    short* wsb = (short*)d_ws;
    cvt_weights<<<32, 256, 0, stream>>>(W1, W2, wsb);
    bloom_mlp<true><<<NBLK, 256, 0, stream>>>(X, R, W1, b1, W2, b2, wsb, out);
}

// Round 25
// 72.453 us; speedup vs baseline: 1.5737x; 1.5737x over previous
//
#include <hip/hip_runtime.h>
#include <hip/hip_bf16.h>

// Bloom MLP fused: h=X@W1^T+b1; g=gelu_tanh(h); out=g@W2^T+b2+residual
// X:[262144,64] f32, W1:[256,64], W2:[64,256], out:[262144,64] f32.
//
// Round 25 = round 24 with ONE change: __launch_bounds__(256,1).
// r24's pipeline (tile-1 X in flight under tile-0 compute) never ran: under
// (256,4) the allocator pins to the 64-VGPR tier and spilled xB to scratch
// (WRITE 66->200MB) -- the same signature as r5/r9/r10/r21. r15 proved
// (256,1) lets it allocate 116 VGPR spill-free. Expected ~96-110 VGPR here,
// still <=128 so 4 waves/SIMD reachable; LDS (33KB -> 4 blocks/CU) stays the
// residency cap, same occupancy as r22.
// Structure (r22-proven parts): kappa-permuted W2 from global (32KB bf16
// image, L1-hot), W1+b1 in LDS, fused kb-loop (GEMM1->gelu->GEMM2 per kb),
// ONE barrier, nt out-stores, 64 tokens/wave (NBLK=1024), macro-inlined
// tiles with named constant-indexed arrays.

typedef __attribute__((ext_vector_type(8))) short bf16x8;   // MFMA A/B frag
typedef __attribute__((ext_vector_type(4))) float f32x4;    // MFMA C/D frag
typedef __attribute__((ext_vector_type(4))) float f32x4v;   // nt-store vector
typedef __attribute__((ext_vector_type(4))) short short4v;  // packed 4x bf16

#define NBLK 1024    // 1024 blocks * 4 waves * 64 tokens = 262144

__device__ __forceinline__ short f2bf(float x) {
    union { __hip_bfloat16 h; short s; } u;
    u.h = __float2bfloat16(x);      // compiler pairs into v_cvt_pk_bf16_f32
    return u.s;
}

__device__ __forceinline__ float bloom_gelu(float x) {
    // 0.5*x*(1+tanh(0.79788456*(x+0.044715*x^3))) = x*(1 - 1/(e^{2u}+1))
    // 2u*log2(e) = 2.30220842*x + 0.10294325*x^3 -> v_exp_f32 (2^x) direct
    float x2 = x * x;
    float t1 = __builtin_fmaf(0.10294325f, x2, 2.30220842f);
    float e  = __builtin_exp2f(x * t1);
    float r  = __builtin_amdgcn_rcpf(e + 1.0f);
    return x - x * r;
}

// W1 LDS image: [256 rows][64 shorts], 8 slots of 8 shorts per row,
// slot XOR-swizzled by row&7.
__device__ __forceinline__ int w1_off(int row, int slot) {
    return row * 64 + ((slot ^ (row & 7)) << 3);
}

// async global->LDS, 16B per lane; dest lane-linear (base+lane*16)
__device__ __forceinline__ void gload_lds16(const void* src, void* dst) {
    __builtin_amdgcn_global_load_lds(
        (const __attribute__((address_space(1))) void*)src,
        (__attribute__((address_space(3))) void*)dst, 16, 0, 0);
}

// ---- pre-pass: ws image = [W1 swizzled bf16 32KB][W2 kappa-linear bf16 32KB]
// W2 col f bits: [7:4]=t [3:2]=q [1:0]=r -> kappa=[7:5]=t>>1 [4:3]=q [2]=t&1 [1:0]=r
__global__ __launch_bounds__(256) void cvt_weights(
    const float* __restrict__ W1, const float* __restrict__ W2,
    short* __restrict__ wsb)
{
    const int i4 = (blockIdx.x * 256 + threadIdx.x) * 4;   // 0..32764, step 4
    if (i4 < 16384) {
        const int row = i4 >> 6, col = i4 & 63;
        float4 v = *(const float4*)(W1 + i4);
        short4v o;
        o[0]=f2bf(v.x); o[1]=f2bf(v.y); o[2]=f2bf(v.z); o[3]=f2bf(v.w);
        *(short4v*)(wsb + w1_off(row, col >> 3) + (col & 7)) = o;
    } else {
        const int rel = i4 - 16384;
        const int d = rel >> 8, f = rel & 255;             // 4 f share t,q
        const int t = f >> 4, qq = (f >> 2) & 3;
        const int k4 = ((t >> 1) << 5) | (qq << 3) | ((t & 1) << 2);
        float4 v = *(const float4*)(W2 + rel);
        short4v o;
        o[0]=f2bf(v.x); o[1]=f2bf(v.y); o[2]=f2bf(v.z); o[3]=f2bf(v.w);
        *(short4v*)(wsb + 16384 + (d << 8) + k4) = o;      // linear kappa
    }
}

// load one 32-token tile's X into a named float4[2][4] (constant-indexed)
#define LDX(XD, TOKBASE)                                                     \
    _Pragma("unroll")                                                        \
    for (int m_ = 0; m_ < 2; ++m_) {                                         \
        const float* p_ = X + (size_t)((TOKBASE) + 16*m_ + c) * 64 + q*8;    \
        XD[m_][0] = *(const float4*)(p_);                                    \
        XD[m_][1] = *(const float4*)(p_ + 4);                                \
        XD[m_][2] = *(const float4*)(p_ + 32);                               \
        XD[m_][3] = *(const float4*)(p_ + 36);                               \
    }

// convert a named float4[2][4] to a1[2][2] bf16 fragments
#define CVT_A1(XD)                                                           \
    _Pragma("unroll")                                                        \
    for (int m_ = 0; m_ < 2; ++m_)                                           \
        _Pragma("unroll")                                                    \
        for (int kb_ = 0; kb_ < 2; ++kb_) {                                  \
            const float4 lo_ = XD[m_][2*kb_], hi_ = XD[m_][2*kb_ + 1];       \
            bf16x8 f_;                                                       \
            f_[0]=f2bf(lo_.x); f_[1]=f2bf(lo_.y); f_[2]=f2bf(lo_.z);         \
            f_[3]=f2bf(lo_.w); f_[4]=f2bf(hi_.x); f_[5]=f2bf(hi_.y);         \
            f_[6]=f2bf(hi_.z); f_[7]=f2bf(hi_.w);                            \
            a1[m_][kb_] = f_;                                                \
        }

// fused kb pipeline + epilogue for one 32-token tile (uses a1; inline)
#define RUN_TILE(TOK0)                                                       \
    {                                                                        \
        f32x4 acc2[2][4] = {{{0,0,0,0},{0,0,0,0},{0,0,0,0},{0,0,0,0}},       \
                            {{0,0,0,0},{0,0,0,0},{0,0,0,0},{0,0,0,0}}};      \
        _Pragma("unroll")                                                    \
        for (int kb = 0; kb < 8; ++kb) {                                     \
            bf16x8 w2f[4];                                                   \
            _Pragma("unroll")                                                \
            for (int dt = 0; dt < 4; ++dt)                                   \
                w2f[dt] = *(const bf16x8*)&Wb[16384 + (16*dt + c) * 256 +    \
                                              kb*32 + q*8];                  \
            bf16x8 pm[2];                                                    \
            _Pragma("unroll")                                                \
            for (int tt = 0; tt < 2; ++tt) {                                 \
                const int t_  = 2*kb + tt;                                   \
                const int row = 16*t_ + c;                                   \
                const bf16x8 w1a = *(const bf16x8*)&W1lds[w1_off(row, q)];   \
                const bf16x8 w1b = *(const bf16x8*)&W1lds[w1_off(row, 4+q)]; \
                const float4 b1v = *(const float4*)&Bl1[16*t_ + 4*q];        \
                _Pragma("unroll")                                            \
                for (int m = 0; m < 2; ++m) {                                \
                    f32x4 acc = {0.f, 0.f, 0.f, 0.f};                        \
                    acc = __builtin_amdgcn_mfma_f32_16x16x32_bf16(           \
                        w1a, a1[m][0], acc, 0, 0, 0);                        \
                    acc = __builtin_amdgcn_mfma_f32_16x16x32_bf16(           \
                        w1b, a1[m][1], acc, 0, 0, 0);                        \
                    _Pragma("unroll")                                        \
                    for (int r = 0; r < 4; ++r)                              \
                        pm[m][(tt << 2) + r] =                               \
                            f2bf(bloom_gelu(acc[r] + b1v[r]));               \
                }                                                            \
            }                                                                \
            _Pragma("unroll")                                                \
            for (int dt = 0; dt < 4; ++dt)                                   \
                _Pragma("unroll")                                            \
                for (int m = 0; m < 2; ++m)                                  \
                    acc2[m][dt] = __builtin_amdgcn_mfma_f32_16x16x32_bf16(   \
                        w2f[dt], pm[m], acc2[m][dt], 0, 0, 0);               \
        }                                                                    \
        _Pragma("unroll")                                                    \
        for (int m = 0; m < 2; ++m)                                          \
            _Pragma("unroll")                                                \
            for (int dt = 0; dt < 4; ++dt) {                                 \
                const size_t off =                                           \
                    (size_t)((TOK0) + 16*m + c) * 64 + 16*dt + 4*q;          \
                const float4 r4  = *(const float4*)(R + off);                \
                const float4 b2v = *(const float4*)(b2 + 16*dt + 4*q);       \
                f32x4v o;                                                    \
                o[0] = acc2[m][dt][0] + b2v.x + r4.x;                        \
                o[1] = acc2[m][dt][1] + b2v.y + r4.y;                        \
                o[2] = acc2[m][dt][2] + b2v.z + r4.z;                        \
                o[3] = acc2[m][dt][3] + b2v.w + r4.w;                        \
                __builtin_nontemporal_store(o, (f32x4v*)(out + off));        \
            }                                                                \
    }

template<bool PRE>
__global__ __launch_bounds__(256, 1) void bloom_mlp(
    const float* __restrict__ X,  const float* __restrict__ R,
    const float* __restrict__ W1, const float* __restrict__ b1,
    const float* __restrict__ W2, const float* __restrict__ b2,
    const short* __restrict__ Wb, float* __restrict__ out)
{
    __shared__ __align__(16) short W1lds[16384];   // 32 KB swizzled W1
    __shared__ __align__(16) float Bl1[256];       //  1 KB b1

    const int tid  = threadIdx.x;
    const int wid  = tid >> 6;      // wave 0..3 (independent after the barrier)
    const int lane = tid & 63;
    const int q    = lane >> 4;     // 0..3
    const int c    = lane & 15;     // 0..15
    const int tokW = blockIdx.x * 256 + wid * 64;  // wave owns 64 tokens

    // ---- tile-0 X issued now: flies across weight staging ----
    float4 xA[2][4];
    LDX(xA, tokW)

    // ---- stage W1 (32KB) + b1 (1KB) into LDS ----
    if constexpr (PRE) {
#pragma unroll
        for (int k = 0; k < 8; ++k) {
            const int s8 = (k * 256 + tid) * 8;            // short index
            gload_lds16(Wb + s8, &W1lds[s8]);
        }
        if (tid < 64) gload_lds16(b1 + tid * 4, &Bl1[tid * 4]);
    } else {
#pragma unroll
        for (int k = 0; k < 16; ++k) {
            const int i4 = (k * 256 + tid) * 4;            // W1 floats
            const int row = i4 >> 6, col = i4 & 63;
            float4 v = *(const float4*)(W1 + i4);
            short4v o;
            o[0]=f2bf(v.x); o[1]=f2bf(v.y); o[2]=f2bf(v.z); o[3]=f2bf(v.w);
            *(short4v*)&W1lds[w1_off(row, col >> 3) + (col & 7)] = o;
        }
        if (tid < 64) *(float4*)&Bl1[tid * 4] = *(const float4*)(b1 + tid * 4);
    }

    bf16x8 a1[2][2];
    CVT_A1(xA)            // waits only on this wave's tile-0 X

    __syncthreads();   // THE one barrier: W1/b1 staged (drains vm+lgkm)

    // ---- tile-1 X issued NOW: outstanding under all of tile-0 compute ----
    float4 xB[2][4];
    LDX(xB, tokW + 32)

    RUN_TILE(tokW)        // tile 0 (xB loads in flight underneath)

    CVT_A1(xB)            // xB landed long ago
    RUN_TILE(tokW + 32)   // tile 1
}

extern "C" void kernel_launch(void* const* d_in, const int* in_sizes, int n_in,
                              void* d_out, int out_size, void* d_ws, size_t ws_size,
                              hipStream_t stream) {
    const float* X  = (const float*)d_in[0];
    const float* R  = (const float*)d_in[1];
    const float* W1 = (const float*)d_in[2];
    const float* b1 = (const float*)d_in[3];
    const float* W2 = (const float*)d_in[4];
    const float* b2 = (const float*)d_in[5];
    float* out = (float*)d_out;
    (void)in_sizes; (void)n_in; (void)out_size;

    // PRE path requires ws for the bf16 weight image (W1 swz + W2 kappa).
    short* wsb = (short*)d_ws;
    cvt_weights<<<32, 256, 0, stream>>>(W1, W2, wsb);
    bloom_mlp<true><<<NBLK, 256, 0, stream>>>(X, R, W1, b1, W2, b2, wsb, out);
}

// Round 26
// 63.214 us; speedup vs baseline: 1.8037x; 1.1462x over previous
//
#include <hip/hip_runtime.h>
#include <hip/hip_bf16.h>

// Bloom MLP fused: h=X@W1^T+b1; g=gelu_tanh(h); out=g@W2^T+b2+residual
// X:[262144,64] f32, W1:[256,64], W2:[64,256], out:[262144,64] f32.
//
// FINAL (round 26) = round 22 verbatim -- the session best (63.3us timed).
// Structure: kappa-permuted W2 read from global (32KB bf16 image in ws,
// L1-resident, 0 bank conflicts), W1+b1 in LDS (33KB -> 4 blocks/CU),
// fused kb-loop (GEMM1 -> gelu -> GEMM2 per kb; GEMM2's B-fragment IS the
// gelu'd GEMM1 output via the kappa column permutation -- no LDS for G, no
// barriers in the loop), ONE __syncthreads total, (256,4) -> 60 VGPR,
// R hoisted post-barrier, nontemporal out-stores.
//
// Session ledger: 14 single-variable experiments across 3 structures
// (barriers, occupancy 8->26 waves/CU, LDS staging/swizzle, prefetch depth,
// L3/L1 steering, in-flight hoists, tile/block shapes) -- all null or
// negative around 63.3-65.7us. The floor is a latency-structure bound:
// ~18us of issue work + 132MB warm HBM stretched by the X->GEMM1->GELU->
// GEMM2 dependency chain; every concurrency lever hits the VGPR-spill /
// occupancy seesaw (60VGPR/38% <-> 64+spill <-> 112VGPR/21%).

typedef __attribute__((ext_vector_type(8))) short bf16x8;   // MFMA A/B frag
typedef __attribute__((ext_vector_type(4))) float f32x4;    // MFMA C/D frag
typedef __attribute__((ext_vector_type(4))) float f32x4v;   // nt-store vector
typedef __attribute__((ext_vector_type(4))) short short4v;  // packed 4x bf16

#define NBLK 2048    // 2048 blocks * 4 waves * 32 tokens = 262144

__device__ __forceinline__ short f2bf(float x) {
    union { __hip_bfloat16 h; short s; } u;
    u.h = __float2bfloat16(x);      // compiler pairs into v_cvt_pk_bf16_f32
    return u.s;
}

__device__ __forceinline__ float bloom_gelu(float x) {
    // 0.5*x*(1+tanh(0.79788456*(x+0.044715*x^3))) = x*(1 - 1/(e^{2u}+1))
    // 2u*log2(e) = 2.30220842*x + 0.10294325*x^3 -> v_exp_f32 (2^x) direct
    float x2 = x * x;
    float t1 = __builtin_fmaf(0.10294325f, x2, 2.30220842f);
    float e  = __builtin_exp2f(x * t1);
    float r  = __builtin_amdgcn_rcpf(e + 1.0f);
    return x - x * r;
}

// W1 LDS image: [256 rows][64 shorts], 8 slots of 8 shorts per row,
// slot XOR-swizzled by row&7.
__device__ __forceinline__ int w1_off(int row, int slot) {
    return row * 64 + ((slot ^ (row & 7)) << 3);
}

// async global->LDS, 16B per lane; dest lane-linear (base+lane*16)
__device__ __forceinline__ void gload_lds16(const void* src, void* dst) {
    __builtin_amdgcn_global_load_lds(
        (const __attribute__((address_space(1))) void*)src,
        (__attribute__((address_space(3))) void*)dst, 16, 0, 0);
}

// ---- pre-pass: ws image = [W1 swizzled bf16 32KB][W2 kappa-linear bf16 32KB]
// W2 col f bits: [7:4]=t [3:2]=q [1:0]=r -> kappa=[7:5]=t>>1 [4:3]=q [2]=t&1 [1:0]=r
__global__ __launch_bounds__(256) void cvt_weights(
    const float* __restrict__ W1, const float* __restrict__ W2,
    short* __restrict__ wsb)
{
    const int i4 = (blockIdx.x * 256 + threadIdx.x) * 4;   // 0..32764, step 4
    if (i4 < 16384) {
        const int row = i4 >> 6, col = i4 & 63;
        float4 v = *(const float4*)(W1 + i4);
        short4v o;
        o[0]=f2bf(v.x); o[1]=f2bf(v.y); o[2]=f2bf(v.z); o[3]=f2bf(v.w);
        *(short4v*)(wsb + w1_off(row, col >> 3) + (col & 7)) = o;
    } else {
        const int rel = i4 - 16384;
        const int d = rel >> 8, f = rel & 255;             // 4 f share t,q
        const int t = f >> 4, qq = (f >> 2) & 3;
        const int k4 = ((t >> 1) << 5) | (qq << 3) | ((t & 1) << 2);
        float4 v = *(const float4*)(W2 + rel);
        short4v o;
        o[0]=f2bf(v.x); o[1]=f2bf(v.y); o[2]=f2bf(v.z); o[3]=f2bf(v.w);
        *(short4v*)(wsb + 16384 + (d << 8) + k4) = o;      // linear kappa
    }
}

template<bool PRE>
__global__ __launch_bounds__(256, 4) void bloom_mlp(
    const float* __restrict__ X,  const float* __restrict__ R,
    const float* __restrict__ W1, const float* __restrict__ b1,
    const float* __restrict__ W2, const float* __restrict__ b2,
    const short* __restrict__ Wb, float* __restrict__ out)
{
    __shared__ __align__(16) short W1lds[16384];   // 32 KB swizzled W1
    __shared__ __align__(16) float Bl1[256];       //  1 KB b1

    const int tid  = threadIdx.x;
    const int wid  = tid >> 6;      // wave 0..3 (independent after the barrier)
    const int lane = tid & 63;
    const int q    = lane >> 4;     // 0..3
    const int c    = lane & 15;     // 0..15
    const int tok0 = blockIdx.x * 128 + wid * 32;

    // ---- issue X now (8 float4/lane): flies across weight staging ----
    float4 xr[2][4];
#pragma unroll
    for (int m = 0; m < 2; ++m) {
        const float* p = X + (size_t)(tok0 + 16*m + c) * 64 + q*8;
        xr[m][0] = *(const float4*)(p);
        xr[m][1] = *(const float4*)(p + 4);
        xr[m][2] = *(const float4*)(p + 32);
        xr[m][3] = *(const float4*)(p + 36);
    }

    // ---- stage W1 (32KB) + b1 (1KB) into LDS ----
    if constexpr (PRE) {
#pragma unroll
        for (int k = 0; k < 8; ++k) {
            const int s8 = (k * 256 + tid) * 8;            // short index
            gload_lds16(Wb + s8, &W1lds[s8]);
        }
        if (tid < 64) gload_lds16(b1 + tid * 4, &Bl1[tid * 4]);
    } else {
#pragma unroll
        for (int k = 0; k < 16; ++k) {
            const int i4 = (k * 256 + tid) * 4;            // W1 floats
            const int row = i4 >> 6, col = i4 & 63;
            float4 v = *(const float4*)(W1 + i4);
            short4v o;
            o[0]=f2bf(v.x); o[1]=f2bf(v.y); o[2]=f2bf(v.z); o[3]=f2bf(v.w);
            *(short4v*)&W1lds[w1_off(row, col >> 3) + (col & 7)] = o;
        }
        if (tid < 64) *(float4*)&Bl1[tid * 4] = *(const float4*)(b1 + tid * 4);
    }

    // X -> bf16 fragments (lane holds X[tok0+16m+c][kb*32+q*8..+7])
    bf16x8 a1[2][2];
#pragma unroll
    for (int m = 0; m < 2; ++m)
#pragma unroll
        for (int kb = 0; kb < 2; ++kb) {
            const float4 lo = xr[m][2*kb], hi = xr[m][2*kb+1];
            bf16x8 f;
            f[0]=f2bf(lo.x); f[1]=f2bf(lo.y); f[2]=f2bf(lo.z); f[3]=f2bf(lo.w);
            f[4]=f2bf(hi.x); f[5]=f2bf(hi.y); f[6]=f2bf(hi.z); f[7]=f2bf(hi.w);
            a1[m][kb] = f;
        }

    __syncthreads();   // THE one barrier: W1/b1 staged (drains vm+lgkm)

    // ---- R hoisted here: 8 float4 issued before the kb loop ----
    float4 r4h[2][4];
#pragma unroll
    for (int m = 0; m < 2; ++m)
#pragma unroll
        for (int dt = 0; dt < 4; ++dt)
            r4h[m][dt] = *(const float4*)(R + (size_t)(tok0 + 16*m + c) * 64 + 16*dt + 4*q);

    // ================= fused kb pipeline (zero-sync) =================
    f32x4 acc2[2][4] = {{{0,0,0,0},{0,0,0,0},{0,0,0,0},{0,0,0,0}},
                        {{0,0,0,0},{0,0,0,0},{0,0,0,0},{0,0,0,0}}};
#pragma unroll
    for (int kb = 0; kb < 8; ++kb) {
        // W2 fragments from global (L1-resident image), issued first
        bf16x8 w2f[4];
#pragma unroll
        for (int dt = 0; dt < 4; ++dt) {
            if constexpr (PRE) {
                w2f[dt] = *(const bf16x8*)&Wb[16384 + (16*dt + c) * 256 + kb*32 + q*8];
            } else {
                const float* p = W2 + (size_t)(16*dt + c) * 256 + kb*32 + 4*q;
                float4 lo = *(const float4*)p, hi = *(const float4*)(p + 16);
                bf16x8 f;
                f[0]=f2bf(lo.x); f[1]=f2bf(lo.y); f[2]=f2bf(lo.z); f[3]=f2bf(lo.w);
                f[4]=f2bf(hi.x); f[5]=f2bf(hi.y); f[6]=f2bf(hi.z); f[7]=f2bf(hi.w);
                w2f[dt] = f;
            }
        }

        // GEMM1 + gelu for the two t's feeding this kb
        bf16x8 pm[2];
#pragma unroll
        for (int tt = 0; tt < 2; ++tt) {
            const int t   = 2*kb + tt;
            const int row = 16*t + c;
            const bf16x8 w1a = *(const bf16x8*)&W1lds[w1_off(row, q)];      // k 0..31
            const bf16x8 w1b = *(const bf16x8*)&W1lds[w1_off(row, 4 + q)];  // k 32..63
            const float4 b1v = *(const float4*)&Bl1[16*t + 4*q];
#pragma unroll
            for (int m = 0; m < 2; ++m) {
                f32x4 acc = {0.f, 0.f, 0.f, 0.f};
                acc = __builtin_amdgcn_mfma_f32_16x16x32_bf16(w1a, a1[m][0], acc, 0, 0, 0);
                acc = __builtin_amdgcn_mfma_f32_16x16x32_bf16(w1b, a1[m][1], acc, 0, 0, 0);
                // D[f=16t+4q+r][token=c] -> kappa slot pm[m][tt*4+r]
#pragma unroll
                for (int r = 0; r < 4; ++r)
                    pm[m][(tt << 2) + r] = f2bf(bloom_gelu(acc[r] + b1v[r]));
            }
        }

        // GEMM2: consume pm immediately (kappa: pm IS the B-fragment)
#pragma unroll
        for (int dt = 0; dt < 4; ++dt)
#pragma unroll
            for (int m = 0; m < 2; ++m)
                acc2[m][dt] = __builtin_amdgcn_mfma_f32_16x16x32_bf16(
                    w2f[dt], pm[m], acc2[m][dt], 0, 0, 0);
    }

    // ---- epilogue: D[d=16dt+4q+r][token=c]; R pre-loaded; nt store ----
#pragma unroll
    for (int m = 0; m < 2; ++m)
#pragma unroll
        for (int dt = 0; dt < 4; ++dt) {
            const size_t off = (size_t)(tok0 + 16*m + c) * 64 + 16*dt + 4*q;
            const float4 b2v = *(const float4*)(b2 + 16*dt + 4*q);
            f32x4v o;
            o[0] = acc2[m][dt][0] + b2v.x + r4h[m][dt].x;
            o[1] = acc2[m][dt][1] + b2v.y + r4h[m][dt].y;
            o[2] = acc2[m][dt][2] + b2v.z + r4h[m][dt].z;
            o[3] = acc2[m][dt][3] + b2v.w + r4h[m][dt].w;
            __builtin_nontemporal_store(o, (f32x4v*)(out + off));
        }
}

extern "C" void kernel_launch(void* const* d_in, const int* in_sizes, int n_in,
                              void* d_out, int out_size, void* d_ws, size_t ws_size,
                              hipStream_t stream) {
    const float* X  = (const float*)d_in[0];
    const float* R  = (const float*)d_in[1];
    const float* W1 = (const float*)d_in[2];
    const float* b1 = (const float*)d_in[3];
    const float* W2 = (const float*)d_in[4];
    const float* b2 = (const float*)d_in[5];
    float* out = (float*)d_out;
    (void)in_sizes; (void)n_in; (void)out_size;

    if (ws_size >= 65536) {
        short* wsb = (short*)d_ws;
        cvt_weights<<<32, 256, 0, stream>>>(W1, W2, wsb);
        bloom_mlp<true><<<NBLK, 256, 0, stream>>>(X, R, W1, b1, W2, b2, wsb, out);
    } else {
        bloom_mlp<false><<<NBLK, 256, 0, stream>>>(X, R, W1, b1, W2, b2, nullptr, out);
    }
}